// Round 16
// baseline (89.725 us; speedup 1.0000x reference)
//
#include <hip/hip_runtime.h>

// Nearest-prototype argmin: N=500k, K=256, D=64, fp32.
// R16: fully AUTONOMOUS waves. R13-R15 probes proved the 2-wave proto-split
// structure idles ~75% on coupling (barrier+LDS exchange+wave0-only merge).
// Now each wave holds ALL 256 protos (ah[16][2]=128 VGPR, 2 waves/SIMD) and
// owns its point-groups outright: no per-iter barrier, no merge. musq seed:
// -musq/2 staged once in LDS; per-iter ds_read_b128 lands straight in the
// MFMA C operand (broadcast addresses, 0 VALU). MFMA/iter 48->32 (am pass
// deleted). Packed-index argmax + margin 0.017 + LDS-staged exact-fp32
// fixup unchanged (absmax=0 heritage R12-R15).

#define DIM 64
#define NPROTO 256
#define NBLK 512            // x4 waves/block = 2048 autonomous waves
#define GSZ 16              // points per iteration
#define MARGIN_ACC 0.017f

using f32x4 = __attribute__((ext_vector_type(4))) float;
using f16x8 = __attribute__((ext_vector_type(8))) _Float16;

__device__ __forceinline__ f16x8 cvt8(float4 a, float4 b) {
    f16x8 r;
    r[0] = (_Float16)a.x; r[1] = (_Float16)a.y;
    r[2] = (_Float16)a.z; r[3] = (_Float16)a.w;
    r[4] = (_Float16)b.x; r[5] = (_Float16)b.y;
    r[6] = (_Float16)b.z; r[7] = (_Float16)b.w;
    return r;
}

__attribute__((amdgpu_waves_per_eu(2, 4)))
__global__ void __launch_bounds__(256)
argmin_mfma_kernel(const float* __restrict__ X,
                   const float* __restrict__ mus,
                   int* __restrict__ out,
                   unsigned* __restrict__ ws_count,
                   int* __restrict__ ws_list,
                   int use_list, int n) {
    __shared__ __align__(16) float s_seed[NPROTO];  // -0.5*musq

    const int tid = threadIdx.x;   // 256 = 4 autonomous waves
    const int w = tid >> 6;
    const int l = tid & 63;
    const int lp = l & 15;         // A-row / B-col lane index
    const int lg = l >> 4;         // k-group

    // ---- prologue: ALL 256 protos into ah[16][2] (R11-proven layout);
    // musq via fmaf chain (same order as R12-15) + lg-shuffle combine ----
    f16x8 ah[16][2];
#pragma unroll
    for (int p = 0; p < 16; ++p) {
        const float* src = mus + (size_t)(p * 16 + lp) * DIM + lg * 8;
        const float4 a = *(const float4*)(src);
        const float4 b = *(const float4*)(src + 4);
        const float4 c = *(const float4*)(src + 32);
        const float4 d = *(const float4*)(src + 36);
        ah[p][0] = cvt8(a, b);
        ah[p][1] = cvt8(c, d);
        float s = 0.f;
        s = fmaf(a.x, a.x, fmaf(a.y, a.y, fmaf(a.z, a.z, fmaf(a.w, a.w, s))));
        s = fmaf(b.x, b.x, fmaf(b.y, b.y, fmaf(b.z, b.z, fmaf(b.w, b.w, s))));
        s = fmaf(c.x, c.x, fmaf(c.y, c.y, fmaf(c.z, c.z, fmaf(c.w, c.w, s))));
        s = fmaf(d.x, d.x, fmaf(d.y, d.y, fmaf(d.z, d.z, fmaf(d.w, d.w, s))));
        s += __shfl_xor(s, 16);
        s += __shfl_xor(s, 32);
        if (w == 0 && lg == 0) s_seed[p * 16 + lp] = -0.5f * s;
    }
    __syncthreads();   // the ONLY barrier: publish s_seed

    // ---- group range per GLOBAL wave ----
    const int ngroups = (n + GSZ - 1) / GSZ;   // 31250
    const int NW = NBLK * 4;
    const int gwid = blockIdx.x * 4 + w;
    const int q = ngroups / NW, rr = ngroups % NW;
    const int g0 = gwid * q + (gwid < rr ? gwid : rr);
    const int cnt = q + (gwid < rr ? 1 : 0);

    const int kofs = 255 - lg * 4;   // packed value = 255 - k

    // prefetch group g0 (lane: row g*16+lp, dims lg*8 + kt*32)
    float4 xr0, xr1, xr2, xr3;
    if (cnt > 0) {
        int row = g0 * GSZ + lp; row = (row < n) ? row : (n - 1);
        const float* rp = X + (size_t)row * DIM + lg * 8;
        xr0 = *(const float4*)(rp);
        xr1 = *(const float4*)(rp + 4);
        xr2 = *(const float4*)(rp + 32);
        xr3 = *(const float4*)(rp + 36);
    }

    for (int it = 0; it < cnt; ++it) {
        const int g = g0 + it;
        const bool more = (it + 1 < cnt);

        const f16x8 bx0 = cvt8(xr0, xr1);
        const f16x8 bx1 = cvt8(xr2, xr3);

        // issue next group's loads; consumed next iteration (no barriers
        // anywhere -> they stay in flight a full ~1200-cyc body)
        if (more) {
            int row = (g + 1) * GSZ + lp; row = (row < n) ? row : (n - 1);
            const float* rp = X + (size_t)row * DIM + lg * 8;
            xr0 = *(const float4*)(rp);
            xr1 = *(const float4*)(rp + 4);
            xr2 = *(const float4*)(rp + 32);
            xr3 = *(const float4*)(rp + 36);
        }

        float b1 = -3.4e38f, b2 = -3.4e38f;
#pragma unroll
        for (int p = 0; p < 16; ++p) {
            // seed = -musq/2 for this lane's 4 slots, straight into C
            const f32x4 seed = *(const f32x4*)&s_seed[p * 16 + lg * 4];
            f32x4 acc = __builtin_amdgcn_mfma_f32_16x16x32_f16(
                ah[p][0], bx0, seed, 0, 0, 0);
            acc = __builtin_amdgcn_mfma_f32_16x16x32_f16(ah[p][1], bx1, acc,
                                                         0, 0, 0);
            // pack index into low 8 mantissa bits (bits cleared: no carry)
            float pv[4];
#pragma unroll
            for (int r = 0; r < 4; ++r) {
                unsigned u = __float_as_uint(acc[r]);
                u = (u & 0xFFFFFF00u) + (unsigned)(kofs - p * 16 - r);
                pv[r] = __uint_as_float(u);
            }
            const float t1a = fmaxf(pv[0], pv[1]), t2a = fminf(pv[0], pv[1]);
            const float t1b = fmaxf(pv[2], pv[3]), t2b = fminf(pv[2], pv[3]);
            const float p1 = fmaxf(t1a, t1b);
            const float p2 = fmaxf(fminf(t1a, t1b), fmaxf(t2a, t2b));
            const float nb2 = fmaxf(fminf(b1, p1), fmaxf(b2, p2));
            b1 = fmaxf(b1, p1);
            b2 = nb2;
        }
        // cross-lane over lg (4 lanes share point lp); butterfly -> all lanes
#pragma unroll
        for (int m = 16; m <= 32; m <<= 1) {
            const float o1 = __shfl_xor(b1, m);
            const float o2 = __shfl_xor(b2, m);
            const float nb2 = fmaxf(fminf(b1, o1), fmaxf(b2, o2));
            b1 = fmaxf(b1, o1);
            b2 = nb2;
        }

        bool fl = false;
        const int i = g * GSZ + l;   // valid for l < GSZ
        if (l < GSZ && i < n) {
            const unsigned u1 = __float_as_uint(b1);
            const int k1 = 255 - (int)(u1 & 0xFFu);
            const float f1 = __uint_as_float(u1 & 0xFFFFFF00u);
            const float f2 =
                __uint_as_float(__float_as_uint(b2) & 0xFFFFFF00u);
            const bool close = (f1 - f2) < MARGIN_ACC;
            if (use_list) {
                out[i] = k1;
                fl = close;
            } else {
                out[i] = (int)((unsigned)k1 | (close ? 0x80000000u : 0u));
            }
        }
        if (use_list) {
            const unsigned long long mask = __ballot(fl);
            if (mask) {
                unsigned base = 0;
                if (l == 0)
                    base = atomicAdd(ws_count, (unsigned)__popcll(mask));
                base = __shfl(base, 0);
                if (fl)
                    ws_list[base + __popcll(mask & ((1ull << l) - 1))] = i;
            }
        }
    }
}

#define MSTRIDE 65   // padded row stride: bank (l+d)%32, 2 lanes/bank = free

// LDS-staged exact-fp32 fixup (unchanged from R13/R15): stage all mus
// (+msq, R2 4-stripe order) into LDS once per block; one point per wave.
__global__ void __launch_bounds__(256)
fixup_lds_kernel(const float* __restrict__ X, const float* __restrict__ mus,
                 const unsigned* __restrict__ ws_count,
                 const int* __restrict__ ws_list, int* __restrict__ out) {
    __shared__ float s_mu[NPROTO * MSTRIDE];  // 65 KB
    __shared__ float s_msq[NPROTO];

    const int tid = threadIdx.x;
    {
        const float4* mr = (const float4*)(mus + (size_t)tid * DIM);
        float q0 = 0.f, q1 = 0.f, q2 = 0.f, q3 = 0.f;
#pragma unroll
        for (int qq = 0; qq < 16; ++qq) {
            const float4 mv = mr[qq];
            const int base = tid * MSTRIDE + qq * 4;
            s_mu[base]     = mv.x;
            s_mu[base + 1] = mv.y;
            s_mu[base + 2] = mv.z;
            s_mu[base + 3] = mv.w;
            q0 = fmaf(mv.x, mv.x, q0);
            q1 = fmaf(mv.y, mv.y, q1);
            q2 = fmaf(mv.z, mv.z, q2);
            q3 = fmaf(mv.w, mv.w, q3);
        }
        s_msq[tid] = (q0 + q1) + (q2 + q3);
    }
    __syncthreads();

    const int l = tid & 63;
    const int gw = (int)((blockIdx.x * blockDim.x + tid) >> 6);
    const int NW = (int)((gridDim.x * blockDim.x) >> 6);
    const int nf = (int)*ws_count;

    for (int j = gw; j < nf; j += NW) {
        const int pt = ws_list[j];
        const float4* xr = (const float4*)(X + (size_t)pt * DIM);
        float4 xv[16];
        float a0 = 0.f, a1 = 0.f, a2 = 0.f, a3 = 0.f;
#pragma unroll
        for (int qq = 0; qq < 16; ++qq) {
            xv[qq] = xr[qq];
            a0 = fmaf(xv[qq].x, xv[qq].x, a0);
            a1 = fmaf(xv[qq].y, xv[qq].y, a1);
            a2 = fmaf(xv[qq].z, xv[qq].z, a2);
            a3 = fmaf(xv[qq].w, xv[qq].w, a3);
        }
        const float xsq = (a0 + a1) + (a2 + a3);
        float b1 = 3.4e38f;
        int k1 = 0;
#pragma unroll
        for (int e = 0; e < 4; ++e) {
            const int p = e * 64 + l;           // k ascending per lane
            const float* mr = &s_mu[p * MSTRIDE];
            float d0 = 0.f, d1 = 0.f, d2 = 0.f, d3 = 0.f;
#pragma unroll
            for (int qq = 0; qq < 16; ++qq) {
                d0 = fmaf(mr[qq * 4],     xv[qq].x, d0);
                d1 = fmaf(mr[qq * 4 + 1], xv[qq].y, d1);
                d2 = fmaf(mr[qq * 4 + 2], xv[qq].z, d2);
                d3 = fmaf(mr[qq * 4 + 3], xv[qq].w, d3);
            }
            const float dot = (d0 + d1) + (d2 + d3);
            const float dd = (xsq - 2.0f * dot) + s_msq[p];
            if (dd < b1) { b1 = dd; k1 = p; }   // strict <: first-min
        }
#pragma unroll
        for (int mm = 1; mm < 64; mm <<= 1) {
            const float ob = __shfl_xor(b1, mm);
            const int ok = __shfl_xor(k1, mm);
            if (ob < b1 || (ob == b1 && ok < k1)) { b1 = ob; k1 = ok; }
        }
        if (l == 0) out[pt] = k1;
    }
}

// Exact-fp32 wave-cooperative recompute (fallback scan path only).
__device__ __forceinline__ int recompute_point(const float* __restrict__ X,
                                               const float* __restrict__ mus,
                                               int pt, int l) {
    const float4* xr = (const float4*)(X + (size_t)pt * DIM);
    float4 xv[16];
    float xa0 = 0.f, xa1 = 0.f, xa2 = 0.f, xa3 = 0.f;
#pragma unroll
    for (int qq = 0; qq < 16; ++qq) {
        xv[qq] = xr[qq];
        xa0 = fmaf(xv[qq].x, xv[qq].x, xa0);
        xa1 = fmaf(xv[qq].y, xv[qq].y, xa1);
        xa2 = fmaf(xv[qq].z, xv[qq].z, xa2);
        xa3 = fmaf(xv[qq].w, xv[qq].w, xa3);
    }
    const float xsq = (xa0 + xa1) + (xa2 + xa3);
    float b1 = 3.4e38f; int k1 = 0;
#pragma unroll
    for (int e = 0; e < 4; ++e) {
        const int p = l * 4 + e;
        const float4* mr = (const float4*)(mus + (size_t)p * DIM);
        float d0 = 0.f, d1 = 0.f, d2a = 0.f, d3 = 0.f;
        float q0 = 0.f, q1 = 0.f, q2 = 0.f, q3 = 0.f;
#pragma unroll
        for (int qq = 0; qq < 16; ++qq) {
            const float4 mv = mr[qq];
            d0 = fmaf(mv.x, xv[qq].x, d0);
            d1 = fmaf(mv.y, xv[qq].y, d1);
            d2a = fmaf(mv.z, xv[qq].z, d2a);
            d3 = fmaf(mv.w, xv[qq].w, d3);
            q0 = fmaf(mv.x, mv.x, q0);
            q1 = fmaf(mv.y, mv.y, q1);
            q2 = fmaf(mv.z, mv.z, q2);
            q3 = fmaf(mv.w, mv.w, q3);
        }
        const float dot = (d0 + d1) + (d2a + d3);
        const float msq = (q0 + q1) + (q2 + q3);
        const float dd = (xsq - 2.0f * dot) + msq;
        if (dd < b1) { b1 = dd; k1 = p; }
    }
#pragma unroll
    for (int mm = 1; mm < 64; mm <<= 1) {
        const float ob = __shfl_xor(b1, mm);
        const int ok = __shfl_xor(k1, mm);
        if (ob < b1 || (ob == b1 && ok < k1)) { b1 = ob; k1 = ok; }
    }
    return k1;
}

// Fallback scan fixup (flag bit 31 in out), used if ws too small.
__global__ void __launch_bounds__(256)
fixup_scan_kernel(const float* __restrict__ X, const float* __restrict__ mus,
                  int* __restrict__ out, int n) {
    const int gw = (int)((blockIdx.x * blockDim.x + threadIdx.x) >> 6);
    const int l = threadIdx.x & 63;
    const int NW = (int)((gridDim.x * blockDim.x) >> 6);
    const int chunk = (n + NW - 1) / NW;
    const int base = gw * chunk;
    const int end = (base + chunk < n) ? (base + chunk) : n;
    for (int s = base; s < end; s += 64) {
        const int i = s + l;
        const int v = (i < end) ? out[i] : 0;
        const bool flg = (i < end) && ((unsigned)v & 0x80000000u);
        unsigned long long m = __ballot(flg);
        while (m) {
            const int src = (int)__ffsll((unsigned long long)m) - 1;
            m &= m - 1;
            const int pt = __shfl(i, src);
            const int k1 = recompute_point(X, mus, pt, l);
            if (l == 0) out[pt] = k1;
        }
    }
}

extern "C" void kernel_launch(void* const* d_in, const int* in_sizes, int n_in,
                              void* d_out, int out_size, void* d_ws, size_t ws_size,
                              hipStream_t stream) {
    const float* X = (const float*)d_in[0];
    const float* mus = (const float*)d_in[1];
    int* out = (int*)d_out;
    const int n = in_sizes[0] / DIM;  // 500000

    unsigned* ws_count = (unsigned*)d_ws;
    int* ws_list = (int*)((char*)d_ws + 16);
    const int use_list = (ws_size >= 16 + (size_t)n * 4) ? 1 : 0;

    if (use_list) {
        hipMemsetAsync(d_ws, 0, 16, stream);  // reset append counter
    }

    argmin_mfma_kernel<<<NBLK, 256, 0, stream>>>(X, mus, out, ws_count,
                                                 ws_list, use_list, n);
    if (use_list) {
        fixup_lds_kernel<<<512, 256, 0, stream>>>(X, mus, ws_count, ws_list,
                                                  out);
    } else {
        fixup_scan_kernel<<<512, 256, 0, stream>>>(X, mus, out, n);
    }
}

// Round 17
// 77.276 us; speedup vs baseline: 1.1611x; 1.1611x over previous
//
#include <hip/hip_runtime.h>

// Nearest-prototype argmin: N=500k, K=256, D=64, fp32.
// R17 = R15 (2-wave proto-split, packed argmax, margin+LDS fixup) with the
// iteration widened to 32 POINTS (two independent 16-pt groups): the two
// groups' MFMA/pack/shuffle chains interleave (ILP over the serial
// latencies R13-R15 proved dominant) and barrier/merge/atomic are paid per
// 32 points. Seed via LDS table read straight into MFMA C (R16-proven,
// absmax=0), dropping the am/bones pass: 2 MFMA per p per group. VGPR
// budget counted: ah32 + xpre32 + bx16 + misc ~= 120 < 256 (no spill; R8/
// R12/R16 lesson). n = 15625*32 exactly.

#define DIM 64
#define NPROTO 256
#define NBLK 1024
#define MARGIN_ACC 0.017f

using f32x4 = __attribute__((ext_vector_type(4))) float;
using f16x8 = __attribute__((ext_vector_type(8))) _Float16;

__device__ __forceinline__ f16x8 cvt8(float4 a, float4 b) {
    f16x8 r;
    r[0] = (_Float16)a.x; r[1] = (_Float16)a.y;
    r[2] = (_Float16)a.z; r[3] = (_Float16)a.w;
    r[4] = (_Float16)b.x; r[5] = (_Float16)b.y;
    r[6] = (_Float16)b.z; r[7] = (_Float16)b.w;
    return r;
}

// barrier that does NOT drain vmcnt (R15-proven): prefetch stays in flight.
__device__ __forceinline__ void barrier_keep_vmcnt() {
    asm volatile("s_waitcnt lgkmcnt(0)" ::: "memory");
    __builtin_amdgcn_s_barrier();
    __builtin_amdgcn_sched_barrier(0);
}

// pack slot indices into acc's low 8 mantissa bits, top-2 tree, running max
#define PACK_TREE(acc, b1, b2)                                          \
    {                                                                   \
        float pv[4];                                                    \
        _Pragma("unroll")                                               \
        for (int r = 0; r < 4; ++r) {                                   \
            unsigned u = __float_as_uint(acc[r]);                       \
            u = (u & 0xFFFFFF00u) + (unsigned)(kofs - p * 16 - r);      \
            pv[r] = __uint_as_float(u);                                 \
        }                                                               \
        const float t1a = fmaxf(pv[0], pv[1]), t2a = fminf(pv[0], pv[1]);\
        const float t1b = fmaxf(pv[2], pv[3]), t2b = fminf(pv[2], pv[3]);\
        const float p1 = fmaxf(t1a, t1b);                               \
        const float p2 = fmaxf(fminf(t1a, t1b), fmaxf(t2a, t2b));       \
        const float nb2 = fmaxf(fminf(b1, p1), fmaxf(b2, p2));          \
        b1 = fmaxf(b1, p1);                                             \
        b2 = nb2;                                                       \
    }

__attribute__((amdgpu_waves_per_eu(2, 4)))
__global__ void __launch_bounds__(128)
argmin_mfma_kernel(const float* __restrict__ X,
                   const float* __restrict__ mus,
                   int* __restrict__ out,
                   unsigned* __restrict__ ws_count,
                   int* __restrict__ ws_list,
                   int use_list, int n) {
    __shared__ __align__(16) float s_seed[NPROTO];  // -0.5*musq
    __shared__ uint2 s_pair[2][32];                 // 512 B

    const int tid = threadIdx.x;   // block = 128 = 2 waves
    const int w = tid >> 6;        // wave 0: protos 0-127, wave 1: 128-255
    const int l = tid & 63;
    const int lp = l & 15;         // A-row / B-col lane index
    const int lg = l >> 4;         // k-group

    // ---- A-frags: 128 protos x K64 fp16 (proven layout); seed table ----
    f16x8 ah[8][2];
#pragma unroll
    for (int p = 0; p < 8; ++p) {
        const float* src = mus + (size_t)(w * 128 + p * 16 + lp) * DIM + lg * 8;
        const float4 a = *(const float4*)(src);
        const float4 b = *(const float4*)(src + 4);
        const float4 c = *(const float4*)(src + 32);
        const float4 d = *(const float4*)(src + 36);
        ah[p][0] = cvt8(a, b);
        ah[p][1] = cvt8(c, d);
        float s = 0.f;
        s = fmaf(a.x, a.x, fmaf(a.y, a.y, fmaf(a.z, a.z, fmaf(a.w, a.w, s))));
        s = fmaf(b.x, b.x, fmaf(b.y, b.y, fmaf(b.z, b.z, fmaf(b.w, b.w, s))));
        s = fmaf(c.x, c.x, fmaf(c.y, c.y, fmaf(c.z, c.z, fmaf(c.w, c.w, s))));
        s = fmaf(d.x, d.x, fmaf(d.y, d.y, fmaf(d.z, d.z, fmaf(d.w, d.w, s))));
        s += __shfl_xor(s, 16);
        s += __shfl_xor(s, 32);
        if (lg == 0) s_seed[w * 128 + p * 16 + lp] = -0.5f * s;
    }
    __syncthreads();   // publish seed table (one-time)

    // ---- 32-point group range for this block ----
    const int ng2 = (n + 31) / 32;   // 15625
    const int q = ng2 / NBLK, rr = ng2 % NBLK;
    const int bid = blockIdx.x;
    const int g0 = bid * q + (bid < rr ? bid : rr);
    const int cnt = q + (bid < rr ? 1 : 0);

    const int kofs = 255 - w * 128 - lg * 4;   // packed value = 255 - k
    const int sbase = w * 128 + lg * 4;

    // prefetch group-pair g0: group A rows g*32+lp, group B rows g*32+16+lp
    float4 xa0, xa1, xa2, xa3, xb0, xb1, xb2, xb3;
    if (cnt > 0) {
        int rA = g0 * 32 + lp;      rA = (rA < n) ? rA : (n - 1);
        int rB = g0 * 32 + 16 + lp; rB = (rB < n) ? rB : (n - 1);
        const float* pA = X + (size_t)rA * DIM + lg * 8;
        const float* pB = X + (size_t)rB * DIM + lg * 8;
        xa0 = *(const float4*)(pA);      xa1 = *(const float4*)(pA + 4);
        xa2 = *(const float4*)(pA + 32); xa3 = *(const float4*)(pA + 36);
        xb0 = *(const float4*)(pB);      xb1 = *(const float4*)(pB + 4);
        xb2 = *(const float4*)(pB + 32); xb3 = *(const float4*)(pB + 36);
    }

    for (int it = 0; it < cnt; ++it) {
        const int g = g0 + it;
        const int par = it & 1;
        const bool more = (it + 1 < cnt);

        const f16x8 bxA0 = cvt8(xa0, xa1), bxA1 = cvt8(xa2, xa3);
        const f16x8 bxB0 = cvt8(xb0, xb1), bxB1 = cvt8(xb2, xb3);

        // issue next pair's loads; consumed next iteration (survive the
        // non-draining barrier)
        if (more) {
            int rA = (g + 1) * 32 + lp;      rA = (rA < n) ? rA : (n - 1);
            int rB = (g + 1) * 32 + 16 + lp; rB = (rB < n) ? rB : (n - 1);
            const float* pA = X + (size_t)rA * DIM + lg * 8;
            const float* pB = X + (size_t)rB * DIM + lg * 8;
            xa0 = *(const float4*)(pA);      xa1 = *(const float4*)(pA + 4);
            xa2 = *(const float4*)(pA + 32); xa3 = *(const float4*)(pA + 36);
            xb0 = *(const float4*)(pB);      xb1 = *(const float4*)(pB + 4);
            xb2 = *(const float4*)(pB + 32); xb3 = *(const float4*)(pB + 36);
        }

        float b1A = -3.4e38f, b2A = -3.4e38f;
        float b1B = -3.4e38f, b2B = -3.4e38f;
#pragma unroll
        for (int p = 0; p < 8; ++p) {
            // seed = -musq/2 straight into C (R16-proven); two independent
            // MFMA chains (A,B) interleave -> latency overlapped
            const f32x4 seed = *(const f32x4*)&s_seed[sbase + p * 16];
            f32x4 accA = __builtin_amdgcn_mfma_f32_16x16x32_f16(
                ah[p][0], bxA0, seed, 0, 0, 0);
            f32x4 accB = __builtin_amdgcn_mfma_f32_16x16x32_f16(
                ah[p][0], bxB0, seed, 0, 0, 0);
            accA = __builtin_amdgcn_mfma_f32_16x16x32_f16(ah[p][1], bxA1,
                                                          accA, 0, 0, 0);
            accB = __builtin_amdgcn_mfma_f32_16x16x32_f16(ah[p][1], bxB1,
                                                          accB, 0, 0, 0);
            PACK_TREE(accA, b1A, b2A)
            PACK_TREE(accB, b1B, b2B)
        }
        // cross-lane over lg; two independent butterflies interleave
#pragma unroll
        for (int m = 16; m <= 32; m <<= 1) {
            const float o1A = __shfl_xor(b1A, m), o2A = __shfl_xor(b2A, m);
            const float o1B = __shfl_xor(b1B, m), o2B = __shfl_xor(b2B, m);
            const float n2A = fmaxf(fminf(b1A, o1A), fmaxf(b2A, o2A));
            const float n2B = fmaxf(fminf(b1B, o1B), fmaxf(b2B, o2B));
            b1A = fmaxf(b1A, o1A); b2A = n2A;
            b1B = fmaxf(b1B, o1B); b2B = n2B;
        }
        if (w == 1 && l < 16) {
            s_pair[par][l] = make_uint2(__float_as_uint(b1A),
                                        __float_as_uint(b2A));
            s_pair[par][16 + l] = make_uint2(__float_as_uint(b1B),
                                             __float_as_uint(b2B));
        }
        barrier_keep_vmcnt();

        bool fl = false;
        const int i = g * 32 + l;   // valid for l < 32
        if (w == 0 && l < 32 && i < n) {
            // lane l<16 holds group A result for point lp=l; lanes 16..31
            // hold group B result for point lp=l-16 -> both match i=g*32+l
            float f1 = (l < 16) ? b1A : b1B;
            float f2 = (l < 16) ? b2A : b2B;
            const uint2 o = s_pair[par][l];
            const float o1 = __uint_as_float(o.x), o2 = __uint_as_float(o.y);
            const float nb2 = fmaxf(fminf(f1, o1), fmaxf(f2, o2));
            f1 = fmaxf(f1, o1);
            f2 = nb2;
            const unsigned u1 = __float_as_uint(f1);
            const int k1 = 255 - (int)(u1 & 0xFFu);
            const float v1 = __uint_as_float(u1 & 0xFFFFFF00u);
            const float v2 =
                __uint_as_float(__float_as_uint(f2) & 0xFFFFFF00u);
            const bool close = (v1 - v2) < MARGIN_ACC;
            if (use_list) {
                out[i] = k1;
                fl = close;
            } else {
                out[i] = (int)((unsigned)k1 | (close ? 0x80000000u : 0u));
            }
        }
        if (use_list) {
            const unsigned long long mask = __ballot(fl);  // wave1: 0
            if (mask) {
                unsigned base = 0;
                if (l == 0)
                    base = atomicAdd(ws_count, (unsigned)__popcll(mask));
                base = __shfl(base, 0);
                if (fl)
                    ws_list[base + __popcll(mask & ((1ull << l) - 1))] = i;
            }
        }
    }
}

#define MSTRIDE 65   // padded row stride: bank (l+d)%32, 2 lanes/bank = free

// LDS-staged exact-fp32 fixup (unchanged from R13/R15): stage all mus
// (+msq, R2 4-stripe order) into LDS once per block; one point per wave.
__global__ void __launch_bounds__(256)
fixup_lds_kernel(const float* __restrict__ X, const float* __restrict__ mus,
                 const unsigned* __restrict__ ws_count,
                 const int* __restrict__ ws_list, int* __restrict__ out) {
    __shared__ float s_mu[NPROTO * MSTRIDE];  // 65 KB
    __shared__ float s_msq[NPROTO];

    const int tid = threadIdx.x;
    {
        const float4* mr = (const float4*)(mus + (size_t)tid * DIM);
        float q0 = 0.f, q1 = 0.f, q2 = 0.f, q3 = 0.f;
#pragma unroll
        for (int qq = 0; qq < 16; ++qq) {
            const float4 mv = mr[qq];
            const int base = tid * MSTRIDE + qq * 4;
            s_mu[base]     = mv.x;
            s_mu[base + 1] = mv.y;
            s_mu[base + 2] = mv.z;
            s_mu[base + 3] = mv.w;
            q0 = fmaf(mv.x, mv.x, q0);
            q1 = fmaf(mv.y, mv.y, q1);
            q2 = fmaf(mv.z, mv.z, q2);
            q3 = fmaf(mv.w, mv.w, q3);
        }
        s_msq[tid] = (q0 + q1) + (q2 + q3);
    }
    __syncthreads();

    const int l = tid & 63;
    const int gw = (int)((blockIdx.x * blockDim.x + tid) >> 6);
    const int NW = (int)((gridDim.x * blockDim.x) >> 6);
    const int nf = (int)*ws_count;

    for (int j = gw; j < nf; j += NW) {
        const int pt = ws_list[j];
        const float4* xr = (const float4*)(X + (size_t)pt * DIM);
        float4 xv[16];
        float a0 = 0.f, a1 = 0.f, a2 = 0.f, a3 = 0.f;
#pragma unroll
        for (int qq = 0; qq < 16; ++qq) {
            xv[qq] = xr[qq];
            a0 = fmaf(xv[qq].x, xv[qq].x, a0);
            a1 = fmaf(xv[qq].y, xv[qq].y, a1);
            a2 = fmaf(xv[qq].z, xv[qq].z, a2);
            a3 = fmaf(xv[qq].w, xv[qq].w, a3);
        }
        const float xsq = (a0 + a1) + (a2 + a3);
        float b1 = 3.4e38f;
        int k1 = 0;
#pragma unroll
        for (int e = 0; e < 4; ++e) {
            const int p = e * 64 + l;           // k ascending per lane
            const float* mr = &s_mu[p * MSTRIDE];
            float d0 = 0.f, d1 = 0.f, d2 = 0.f, d3 = 0.f;
#pragma unroll
            for (int qq = 0; qq < 16; ++qq) {
                d0 = fmaf(mr[qq * 4],     xv[qq].x, d0);
                d1 = fmaf(mr[qq * 4 + 1], xv[qq].y, d1);
                d2 = fmaf(mr[qq * 4 + 2], xv[qq].z, d2);
                d3 = fmaf(mr[qq * 4 + 3], xv[qq].w, d3);
            }
            const float dot = (d0 + d1) + (d2 + d3);
            const float dd = (xsq - 2.0f * dot) + s_msq[p];
            if (dd < b1) { b1 = dd; k1 = p; }   // strict <: first-min
        }
#pragma unroll
        for (int mm = 1; mm < 64; mm <<= 1) {
            const float ob = __shfl_xor(b1, mm);
            const int ok = __shfl_xor(k1, mm);
            if (ob < b1 || (ob == b1 && ok < k1)) { b1 = ob; k1 = ok; }
        }
        if (l == 0) out[pt] = k1;
    }
}

// Exact-fp32 wave-cooperative recompute (fallback scan path only).
__device__ __forceinline__ int recompute_point(const float* __restrict__ X,
                                               const float* __restrict__ mus,
                                               int pt, int l) {
    const float4* xr = (const float4*)(X + (size_t)pt * DIM);
    float4 xv[16];
    float xa0 = 0.f, xa1 = 0.f, xa2 = 0.f, xa3 = 0.f;
#pragma unroll
    for (int qq = 0; qq < 16; ++qq) {
        xv[qq] = xr[qq];
        xa0 = fmaf(xv[qq].x, xv[qq].x, xa0);
        xa1 = fmaf(xv[qq].y, xv[qq].y, xa1);
        xa2 = fmaf(xv[qq].z, xv[qq].z, xa2);
        xa3 = fmaf(xv[qq].w, xv[qq].w, xa3);
    }
    const float xsq = (xa0 + xa1) + (xa2 + xa3);
    float b1 = 3.4e38f; int k1 = 0;
#pragma unroll
    for (int e = 0; e < 4; ++e) {
        const int p = l * 4 + e;
        const float4* mr = (const float4*)(mus + (size_t)p * DIM);
        float d0 = 0.f, d1 = 0.f, d2a = 0.f, d3 = 0.f;
        float q0 = 0.f, q1 = 0.f, q2 = 0.f, q3 = 0.f;
#pragma unroll
        for (int qq = 0; qq < 16; ++qq) {
            const float4 mv = mr[qq];
            d0 = fmaf(mv.x, xv[qq].x, d0);
            d1 = fmaf(mv.y, xv[qq].y, d1);
            d2a = fmaf(mv.z, xv[qq].z, d2a);
            d3 = fmaf(mv.w, xv[qq].w, d3);
            q0 = fmaf(mv.x, mv.x, q0);
            q1 = fmaf(mv.y, mv.y, q1);
            q2 = fmaf(mv.z, mv.z, q2);
            q3 = fmaf(mv.w, mv.w, q3);
        }
        const float dot = (d0 + d1) + (d2a + d3);
        const float msq = (q0 + q1) + (q2 + q3);
        const float dd = (xsq - 2.0f * dot) + msq;
        if (dd < b1) { b1 = dd; k1 = p; }
    }
#pragma unroll
    for (int mm = 1; mm < 64; mm <<= 1) {
        const float ob = __shfl_xor(b1, mm);
        const int ok = __shfl_xor(k1, mm);
        if (ob < b1 || (ob == b1 && ok < k1)) { b1 = ob; k1 = ok; }
    }
    return k1;
}

// Fallback scan fixup (flag bit 31 in out), used if ws too small.
__global__ void __launch_bounds__(256)
fixup_scan_kernel(const float* __restrict__ X, const float* __restrict__ mus,
                  int* __restrict__ out, int n) {
    const int gw = (int)((blockIdx.x * blockDim.x + threadIdx.x) >> 6);
    const int l = threadIdx.x & 63;
    const int NW = (int)((gridDim.x * blockDim.x) >> 6);
    const int chunk = (n + NW - 1) / NW;
    const int base = gw * chunk;
    const int end = (base + chunk < n) ? (base + chunk) : n;
    for (int s = base; s < end; s += 64) {
        const int i = s + l;
        const int v = (i < end) ? out[i] : 0;
        const bool flg = (i < end) && ((unsigned)v & 0x80000000u);
        unsigned long long m = __ballot(flg);
        while (m) {
            const int src = (int)__ffsll((unsigned long long)m) - 1;
            m &= m - 1;
            const int pt = __shfl(i, src);
            const int k1 = recompute_point(X, mus, pt, l);
            if (l == 0) out[pt] = k1;
        }
    }
}

extern "C" void kernel_launch(void* const* d_in, const int* in_sizes, int n_in,
                              void* d_out, int out_size, void* d_ws, size_t ws_size,
                              hipStream_t stream) {
    const float* X = (const float*)d_in[0];
    const float* mus = (const float*)d_in[1];
    int* out = (int*)d_out;
    const int n = in_sizes[0] / DIM;  // 500000

    unsigned* ws_count = (unsigned*)d_ws;
    int* ws_list = (int*)((char*)d_ws + 16);
    const int use_list = (ws_size >= 16 + (size_t)n * 4) ? 1 : 0;

    if (use_list) {
        hipMemsetAsync(d_ws, 0, 16, stream);  // reset append counter
    }

    argmin_mfma_kernel<<<NBLK, 128, 0, stream>>>(X, mus, out, ws_count,
                                                 ws_list, use_list, n);
    if (use_list) {
        fixup_lds_kernel<<<512, 256, 0, stream>>>(X, mus, ws_count, ws_list,
                                                  out);
    } else {
        fixup_scan_kernel<<<512, 256, 0, stream>>>(X, mus, out, n);
    }
}